// Round 19
// baseline (281.503 us; speedup 1.0000x reference)
//
#include <hip/hip_runtime.h>
#include <math.h>
#include <float.h>

#define PH 7
#define RLEN 32   // ints per roi in workspace

// ---- exact integer emulation of the reference's fast-math f32 binning ----
// bin = RN_f32(roi * RN_f32(1/7));  RN_f32(1/7) = 9586981 * 2^-26
#define C7 9586981LL

__device__ __forceinline__ long long round24(long long v) {
    if (v == 0) return 0;
    int L = 64 - __clzll((unsigned long long)v);
    int sh = L - 24;
    if (sh <= 0) return v;
    long long rem  = v & ((1LL << sh) - 1);
    long long base = v >> sh;
    long long half = 1LL << (sh - 1);
    if (rem > half || (rem == half && (base & 1))) base++;
    return base << sh;
}
__device__ __forceinline__ long long bin_q26(int roi) {
    return round24((long long)roi * C7);
}
__device__ __forceinline__ int floor_k(long long b26, int k) {
    long long v = round24((long long)k * b26);
    return (int)(v >> 26);
}
__device__ __forceinline__ int ceil_k(long long b26, int k) {
    long long v = round24((long long)k * b26);
    return (int)((v + ((1LL << 26) - 1)) >> 26);
}

// Per-ROI bounds (ints): [0]=b, [1..7]=hstart, [8..14]=hend,
// [15] = qs | qe<<8 (window column-quad range), [16..22]=ws, [23..29]=we
__global__ void roi_bounds_kernel(const float* __restrict__ rois,
                                  int* __restrict__ wsbuf, int R) {
    int r = blockIdx.x * blockDim.x + threadIdx.x;
    if (r >= R) return;
    const int H = 64, W = 64;
    const float* roi = rois + r * 5;
    int b  = (int)roi[0];
    int x1 = (int)rintf(roi[1] * 0.0625f);
    int y1 = (int)rintf(roi[2] * 0.0625f);
    int x2 = (int)rintf(roi[3] * 0.0625f);
    int y2 = (int)rintf(roi[4] * 0.0625f);

    int roi_w = max(x2 - x1 + 1, 1);
    int roi_h = max(y2 - y1 + 1, 1);
    long long bh = bin_q26(roi_h);
    long long bw = bin_q26(roi_w);

    int* o = wsbuf + r * RLEN;
    o[0] = b;
    int ws0 = 64, we6 = 0;
    #pragma unroll
    for (int i = 0; i < PH; ++i) {
        int hs = min(max(y1 + floor_k(bh, i),     0), H);
        int he = min(max(y1 + ceil_k (bh, i + 1), 0), H);
        int wst = min(max(x1 + floor_k(bw, i),     0), W);
        int wen = min(max(x1 + ceil_k (bw, i + 1), 0), W);
        o[1 + i]  = hs;
        o[8 + i]  = he;
        o[16 + i] = wst;
        o[23 + i] = wen;
        if (i == 0) ws0 = wst;
        if (i == 6) we6 = wen;
    }
    int qs = ws0 >> 2;
    int qe = (we6 + 3) >> 2;
    o[15] = qs | (max(qe, qs) << 8);
}

__device__ __forceinline__ float4 max4(float4 a, float4 b) {
    float4 r;
    r.x = fmaxf(a.x, b.x); r.y = fmaxf(a.y, b.y);
    r.z = fmaxf(a.z, b.z); r.w = fmaxf(a.w, b.w);
    return r;
}

// R17 structure (row carry, dual-tile single pass, double-buffered LDS with
// one-phase-lagged reduce, no barriers) + NARROW-ROI SPECIALIZATION:
// windows <= 4 quads are served by 16ch x 4quad waves (blocks cg>=8 exit),
// halving instructions per channel for ~35% of ROIs. Grid = R * 16.
__global__ __launch_bounds__(256) void roipool_main(
        const float* __restrict__ features,
        const int* __restrict__ wsbuf,
        float* __restrict__ out) {
    __shared__ float U[4][1088];     // 17408 B; std: [8][68] x2, narrow: [16][20] x2

    int r    = blockIdx.x >> 4;      // 16 blocks per roi
    int cg   = blockIdx.x & 15;
    int wv   = threadIdx.x >> 6;
    int lane = threadIdx.x & 63;

    const int* B = wsbuf + r * RLEN; // wave-uniform -> scalar loads
    int b   = B[0];
    int qpk = B[15];
    int qs  = qpk & 255;
    int qe  = qpk >> 8;
    int nq  = qe - qs;

    const float4* f4 = (const float4*)features;
    const float4 NEG4 = make_float4(-FLT_MAX, -FLT_MAX, -FLT_MAX, -FLT_MAX);

    // epilogue lane mapping (groups of 7 lanes; lane<56 active)
    int ech = (lane * 9363) >> 16;   // lane/7 for lane<56
    int epw = lane - ech * 7;
    int ews = B[16 + epw];           // per-lane, L1-hot
    int ewe = B[23 + epw];
    bool eact = lane < 56;

    float* bufA = U[wv];

    if (nq <= 4) {
        // ---------------- narrow path: 16 ch x 4 quads per wave ----------------
        if (cg >= 8) return;         // 8 blocks x 4 waves x 16 ch = 512 ch
        int c0    = (cg << 6) + (wv << 4);
        int chsub = lane >> 2;       // 0..15
        int cq4   = lane & 3;
        int qabs  = qs + cq4;
        bool m0   = qabs < qe;
        int cbase = ((b << 9) + c0 + chsub) << 10;
        float* bufB = U[wv] + 320;   // [16][20] each

        int ewsr = ews - (qs << 2);  // relative cols within the 4-quad tile
        int ewer = ewe - (qs << 2);
        const float* erA0 = bufA + (ech & 7) * 20;
        const float* erA1 = bufA + (8 + (ech & 7)) * 20;
        const float* erB0 = bufB + (ech & 7) * 20;
        const float* erB1 = bufB + (8 + (ech & 7)) * 20;
        float vals0[PH], vals1[PH];
        int phs = 0, phe = 0;
        float4 last0 = NEG4;
        int last_h = -100;

        #pragma unroll
        for (int ph = 0; ph < PH; ++ph) {
            int hs = B[1 + ph], he = B[8 + ph];
            float* cw = (ph & 1) ? bufB : bufA;
            if (m0 && he > hs) {
                bool reuse = (hs == last_h);
                float4 a0 = reuse ? last0 : NEG4;
                int h0 = hs + (reuse ? 1 : 0);
                int nbody = he - h0 - 1;          // rows before the final row
                int idx = cbase + (h0 << 4) + qabs;
                while (nbody >= 4) {              // 4 loads in flight
                    float4 v0 = f4[idx];
                    float4 v1 = f4[idx + 16];
                    float4 v2 = f4[idx + 32];
                    float4 v3 = f4[idx + 48];
                    a0 = max4(a0, max4(max4(v0, v1), max4(v2, v3)));
                    idx += 64; nbody -= 4;
                }
                if (nbody >= 2) {
                    float4 v0 = f4[idx];
                    float4 v1 = f4[idx + 16];
                    a0 = max4(a0, max4(v0, v1));
                    idx += 32; nbody -= 2;
                }
                if (nbody >= 1) a0 = max4(a0, f4[idx]);
                if (he - 1 >= h0) {               // final row: load once, carry
                    last0 = f4[cbase + ((he - 1) << 4) + qabs];
                    a0 = max4(a0, last0);
                }
                last_h = he - 1;
                *(float4*)&cw[chsub * 20 + (cq4 << 2)] = a0;
            }
            if (ph > 0) {                         // lagged reduce of ph-1 (2 rounds)
                const float* e0 = (ph & 1) ? erA0 : erB0;
                const float* e1 = (ph & 1) ? erA1 : erB1;
                bool empty = (phe <= phs) || (ewe <= ews);
                float m = -FLT_MAX;
                int w = ewsr;
                for (; w + 2 <= ewer; w += 2)
                    m = fmaxf(fmaxf(m, e0[w]), e0[w + 1]);
                if (w < ewer) m = fmaxf(m, e0[w]);
                vals0[ph - 1] = empty ? 0.0f : m;
                m = -FLT_MAX;
                w = ewsr;
                for (; w + 2 <= ewer; w += 2)
                    m = fmaxf(fmaxf(m, e1[w]), e1[w + 1]);
                if (w < ewer) m = fmaxf(m, e1[w]);
                vals1[ph - 1] = empty ? 0.0f : m;
            }
            phs = hs; phe = he;
        }
        {   // tail: reduce phase 6 (buffer 6&1=0 -> bufA)
            bool empty = (phe <= phs) || (ewe <= ews);
            float m = -FLT_MAX;
            int w = ewsr;
            for (; w + 2 <= ewer; w += 2)
                m = fmaxf(fmaxf(m, erA0[w]), erA0[w + 1]);
            if (w < ewer) m = fmaxf(m, erA0[w]);
            vals0[PH - 1] = empty ? 0.0f : m;
            m = -FLT_MAX;
            w = ewsr;
            for (; w + 2 <= ewer; w += 2)
                m = fmaxf(fmaxf(m, erA1[w]), erA1[w + 1]);
            if (w < ewer) m = fmaxf(m, erA1[w]);
            vals1[PH - 1] = empty ? 0.0f : m;
        }
        // stage 784 outputs then write coalesced (U[wv] reuse is wave-sync safe)
        float* stage = U[wv];
        if (eact) {
            #pragma unroll
            for (int ph = 0; ph < PH; ++ph) {
                stage[ech * 49 + ph * 7 + epw] = vals0[ph];
                stage[(8 + ech) * 49 + ph * 7 + epw] = vals1[ph];
            }
        }
        size_t obase = ((size_t)(r << 9) + c0) * 49;
        #pragma unroll
        for (int it = 0; it < 13; ++it) {
            int f = (it << 6) + lane;
            if (f < 784) out[obase + f] = stage[f];
        }
        return;
    }

    // ---------------- standard (5-8 quads) / dual (9-16 quads) paths ----------------
    int c0    = (cg << 5) + (wv << 3);
    int chsub = lane >> 3;           // 0..7
    int cq8   = lane & 7;
    bool dual = nq > 8;
    int cbase = ((b << 9) + c0 + chsub) << 10;
    int qabs0 = qs + cq8;
    int qabs1 = qs + 8 + cq8;
    bool m0 = qabs0 < qe;
    bool m1 = qabs1 < qe;
    int qc1 = min(qabs1, 15);        // clamped (dual tile1 only)
    float* bufB = U[wv] + 544;       // [8][68] each

    const float* erowA = bufA + (ech & 7) * 68;
    const float* erowB = bufB + (ech & 7) * 68;
    float vals[PH];
    int phs = 0, phe = 0;

    float4 last0 = NEG4, last1 = NEG4;
    int last_h = -100;

    if (!dual) {
        #pragma unroll
        for (int ph = 0; ph < PH; ++ph) {
            int hs = B[1 + ph], he = B[8 + ph];
            float* cw = (ph & 1) ? bufB : bufA;
            if (m0 && he > hs) {
                bool reuse = (hs == last_h);
                float4 a0 = reuse ? last0 : NEG4;
                int h0 = hs + (reuse ? 1 : 0);
                int nbody = he - h0 - 1;
                int idx = cbase + (h0 << 4) + qabs0;
                while (nbody >= 4) {
                    float4 v0 = f4[idx];
                    float4 v1 = f4[idx + 16];
                    float4 v2 = f4[idx + 32];
                    float4 v3 = f4[idx + 48];
                    a0 = max4(a0, max4(max4(v0, v1), max4(v2, v3)));
                    idx += 64; nbody -= 4;
                }
                if (nbody >= 2) {
                    float4 v0 = f4[idx];
                    float4 v1 = f4[idx + 16];
                    a0 = max4(a0, max4(v0, v1));
                    idx += 32; nbody -= 2;
                }
                if (nbody >= 1) a0 = max4(a0, f4[idx]);
                if (he - 1 >= h0) {
                    last0 = f4[cbase + ((he - 1) << 4) + qabs0];
                    a0 = max4(a0, last0);
                }
                last_h = he - 1;
                *(float4*)&cw[chsub * 68 + (qabs0 << 2)] = a0;
            }
            if (ph > 0) {
                const float* er = (ph & 1) ? erowA : erowB;
                float m = -FLT_MAX;
                int w = ews;
                for (; w + 2 <= ewe; w += 2)
                    m = fmaxf(fmaxf(m, er[w]), er[w + 1]);
                if (w < ewe) m = fmaxf(m, er[w]);
                vals[ph - 1] = ((phe <= phs) || (ewe <= ews)) ? 0.0f : m;
            }
            phs = hs; phe = he;
        }
    } else {
        #pragma unroll
        for (int ph = 0; ph < PH; ++ph) {
            int hs = B[1 + ph], he = B[8 + ph];
            float* cw = (ph & 1) ? bufB : bufA;
            if (he > hs) {
                bool reuse = (hs == last_h);
                float4 a0 = reuse ? last0 : NEG4;
                float4 a1 = reuse ? last1 : NEG4;
                int h0 = hs + (reuse ? 1 : 0);
                int nbody = he - h0 - 1;
                int idx = cbase + (h0 << 4);
                while (nbody >= 2) {
                    float4 v00 = f4[idx + qabs0];
                    float4 v01 = f4[idx + qc1];
                    float4 v10 = f4[idx + 16 + qabs0];
                    float4 v11 = f4[idx + 16 + qc1];
                    a0 = max4(a0, max4(v00, v10));
                    a1 = max4(a1, max4(v01, v11));
                    idx += 32; nbody -= 2;
                }
                if (nbody >= 1) {
                    a0 = max4(a0, f4[idx + qabs0]);
                    a1 = max4(a1, f4[idx + qc1]);
                }
                if (he - 1 >= h0) {
                    int fin = cbase + ((he - 1) << 4);
                    last0 = f4[fin + qabs0];
                    last1 = f4[fin + qc1];
                    a0 = max4(a0, last0);
                    a1 = max4(a1, last1);
                }
                last_h = he - 1;
                *(float4*)&cw[chsub * 68 + (qabs0 << 2)] = a0;
                if (m1) *(float4*)&cw[chsub * 68 + (qabs1 << 2)] = a1;
            }
            if (ph > 0) {
                const float* er = (ph & 1) ? erowA : erowB;
                float m = -FLT_MAX;
                int w = ews;
                for (; w + 2 <= ewe; w += 2)
                    m = fmaxf(fmaxf(m, er[w]), er[w + 1]);
                if (w < ewe) m = fmaxf(m, er[w]);
                vals[ph - 1] = ((phe <= phs) || (ewe <= ews)) ? 0.0f : m;
            }
            phs = hs; phe = he;
        }
    }
    {   // tail: reduce phase 6 (buffer 6&1=0 -> bufA)
        float m = -FLT_MAX;
        int w = ews;
        for (; w + 2 <= ewe; w += 2)
            m = fmaxf(fmaxf(m, erowA[w]), erowA[w + 1]);
        if (w < ewe) m = fmaxf(m, erowA[w]);
        vals[PH - 1] = ((phe <= phs) || (ewe <= ews)) ? 0.0f : m;
    }

    // stage the wave's 392 outputs then write coalesced (wave-sync safe reuse)
    float* stage = U[wv];
    if (eact) {
        #pragma unroll
        for (int ph = 0; ph < PH; ++ph)
            stage[ech * 49 + ph * 7 + epw] = vals[ph];
    }
    size_t obase = ((size_t)(r << 9) + c0) * 49;
    #pragma unroll
    for (int it = 0; it < 7; ++it) {
        int f = (it << 6) + lane;
        if (f < 392) out[obase + f] = stage[f];
    }
}

extern "C" void kernel_launch(void* const* d_in, const int* in_sizes, int n_in,
                              void* d_out, int out_size, void* d_ws, size_t ws_size,
                              hipStream_t stream) {
    const float* features = (const float*)d_in[0];
    const float* rois     = (const float*)d_in[1];
    float* out = (float*)d_out;
    int* wsbuf = (int*)d_ws;

    int R = in_sizes[1] / 5;   // 2000

    roi_bounds_kernel<<<(R + 255) / 256, 256, 0, stream>>>(rois, wsbuf, R);
    roipool_main<<<R * 16, 256, 0, stream>>>(features, wsbuf, out);
}

// Round 20
// 210.807 us; speedup vs baseline: 1.3354x; 1.3354x over previous
//
#include <hip/hip_runtime.h>
#include <math.h>
#include <float.h>

#define PH 7
#define RLEN 32   // ints per roi in workspace

// ---- exact integer emulation of the reference's fast-math f32 binning ----
// bin = RN_f32(roi * RN_f32(1/7));  RN_f32(1/7) = 9586981 * 2^-26
#define C7 9586981LL

__device__ __forceinline__ long long round24(long long v) {
    if (v == 0) return 0;
    int L = 64 - __clzll((unsigned long long)v);
    int sh = L - 24;
    if (sh <= 0) return v;
    long long rem  = v & ((1LL << sh) - 1);
    long long base = v >> sh;
    long long half = 1LL << (sh - 1);
    if (rem > half || (rem == half && (base & 1))) base++;
    return base << sh;
}
__device__ __forceinline__ long long bin_q26(int roi) {
    return round24((long long)roi * C7);
}
__device__ __forceinline__ int floor_k(long long b26, int k) {
    long long v = round24((long long)k * b26);
    return (int)(v >> 26);
}
__device__ __forceinline__ int ceil_k(long long b26, int k) {
    long long v = round24((long long)k * b26);
    return (int)((v + ((1LL << 26) - 1)) >> 26);
}

// Per-ROI bounds (ints): [0]=b, [1..7]=hstart, [8..14]=hend,
// [15] = qs | qe<<8 (window column-quad range), [16..22]=ws, [23..29]=we
__global__ void roi_bounds_kernel(const float* __restrict__ rois,
                                  int* __restrict__ wsbuf, int R) {
    int r = blockIdx.x * blockDim.x + threadIdx.x;
    if (r >= R) return;
    const int H = 64, W = 64;
    const float* roi = rois + r * 5;
    int b  = (int)roi[0];
    int x1 = (int)rintf(roi[1] * 0.0625f);
    int y1 = (int)rintf(roi[2] * 0.0625f);
    int x2 = (int)rintf(roi[3] * 0.0625f);
    int y2 = (int)rintf(roi[4] * 0.0625f);

    int roi_w = max(x2 - x1 + 1, 1);
    int roi_h = max(y2 - y1 + 1, 1);
    long long bh = bin_q26(roi_h);
    long long bw = bin_q26(roi_w);

    int* o = wsbuf + r * RLEN;
    o[0] = b;
    int ws0 = 64, we6 = 0;
    #pragma unroll
    for (int i = 0; i < PH; ++i) {
        int hs = min(max(y1 + floor_k(bh, i),     0), H);
        int he = min(max(y1 + ceil_k (bh, i + 1), 0), H);
        int wst = min(max(x1 + floor_k(bw, i),     0), W);
        int wen = min(max(x1 + ceil_k (bw, i + 1), 0), W);
        o[1 + i]  = hs;
        o[8 + i]  = he;
        o[16 + i] = wst;
        o[23 + i] = wen;
        if (i == 0) ws0 = wst;
        if (i == 6) we6 = wen;
    }
    int qs = ws0 >> 2;
    int qe = (we6 + 3) >> 2;
    o[15] = qs | (max(qe, qs) << 8);
}

__device__ __forceinline__ float4 max4(float4 a, float4 b) {
    float4 r;
    r.x = fmaxf(a.x, b.x); r.y = fmaxf(a.y, b.y);
    r.z = fmaxf(a.z, b.z); r.w = fmaxf(a.w, b.w);
    return r;
}

// R17 structure + narrow-ROI specialization with XCD-PRESERVING channel map:
// narrow block cg (<8) serves exactly the channels std blocks {cg, cg+8}
// would serve -> per-XCD L2 working set identical for all ROI classes.
// Grid = R * 16, 256 threads = 4 independent waves, no barriers.
__global__ __launch_bounds__(256) void roipool_main(
        const float* __restrict__ features,
        const int* __restrict__ wsbuf,
        float* __restrict__ out) {
    __shared__ float U[4][1088];     // 17408 B; std: [8][68] x2, narrow: [16][20] x2

    int r    = blockIdx.x >> 4;      // 16 blocks per roi
    int cg   = blockIdx.x & 15;
    int wv   = threadIdx.x >> 6;
    int lane = threadIdx.x & 63;

    const int* B = wsbuf + r * RLEN; // wave-uniform -> scalar loads
    int b   = B[0];
    int qpk = B[15];
    int qs  = qpk & 255;
    int qe  = qpk >> 8;
    int nq  = qe - qs;

    const float4* f4 = (const float4*)features;
    const float4 NEG4 = make_float4(-FLT_MAX, -FLT_MAX, -FLT_MAX, -FLT_MAX);

    // epilogue lane mapping (groups of 7 lanes; lane<56 active)
    int ech = (lane * 9363) >> 16;   // lane/7 for lane<56
    int epw = lane - ech * 7;
    int ews = B[16 + epw];           // per-lane, L1-hot
    int ewe = B[23 + epw];
    bool eact = lane < 56;

    float* bufA = U[wv];

    if (nq <= 4) {
        // ---- narrow path: 16 ch x 4 quads per wave, XCD-preserving c0 ----
        if (cg >= 8) return;
        // wave wv covers half of std-slice cg (wv<2) or cg+8 (wv>=2)
        int c0 = ((cg + ((wv >> 1) << 3)) << 5) + ((wv & 1) << 4);
        int chsub = lane >> 2;       // 0..15
        int cq4   = lane & 3;
        int qabs  = qs + cq4;
        bool m0   = qabs < qe;
        int cbase = ((b << 9) + c0 + chsub) << 10;
        float* bufB = U[wv] + 320;   // [16][20] each

        int ewsr = ews - (qs << 2);  // relative cols within the 4-quad tile
        int ewer = ewe - (qs << 2);
        const float* erA0 = bufA + (ech & 7) * 20;
        const float* erA1 = bufA + (8 + (ech & 7)) * 20;
        const float* erB0 = bufB + (ech & 7) * 20;
        const float* erB1 = bufB + (8 + (ech & 7)) * 20;
        float vals0[PH], vals1[PH];
        int phs = 0, phe = 0;
        float4 last0 = NEG4;
        int last_h = -100;

        #pragma unroll
        for (int ph = 0; ph < PH; ++ph) {
            int hs = B[1 + ph], he = B[8 + ph];
            float* cw = (ph & 1) ? bufB : bufA;
            if (m0 && he > hs) {
                bool reuse = (hs == last_h);
                float4 a0 = reuse ? last0 : NEG4;
                int h0 = hs + (reuse ? 1 : 0);
                int nbody = he - h0 - 1;          // rows before the final row
                int idx = cbase + (h0 << 4) + qabs;
                while (nbody >= 4) {              // 4 loads in flight
                    float4 v0 = f4[idx];
                    float4 v1 = f4[idx + 16];
                    float4 v2 = f4[idx + 32];
                    float4 v3 = f4[idx + 48];
                    a0 = max4(a0, max4(max4(v0, v1), max4(v2, v3)));
                    idx += 64; nbody -= 4;
                }
                if (nbody >= 2) {
                    float4 v0 = f4[idx];
                    float4 v1 = f4[idx + 16];
                    a0 = max4(a0, max4(v0, v1));
                    idx += 32; nbody -= 2;
                }
                if (nbody >= 1) a0 = max4(a0, f4[idx]);
                if (he - 1 >= h0) {               // final row: load once, carry
                    last0 = f4[cbase + ((he - 1) << 4) + qabs];
                    a0 = max4(a0, last0);
                }
                last_h = he - 1;
                *(float4*)&cw[chsub * 20 + (cq4 << 2)] = a0;
            }
            if (ph > 0) {                         // lagged reduce of ph-1 (2 rounds)
                const float* e0 = (ph & 1) ? erA0 : erB0;
                const float* e1 = (ph & 1) ? erA1 : erB1;
                bool empty = (phe <= phs) || (ewe <= ews);
                float m = -FLT_MAX;
                int w = ewsr;
                for (; w + 2 <= ewer; w += 2)
                    m = fmaxf(fmaxf(m, e0[w]), e0[w + 1]);
                if (w < ewer) m = fmaxf(m, e0[w]);
                vals0[ph - 1] = empty ? 0.0f : m;
                m = -FLT_MAX;
                w = ewsr;
                for (; w + 2 <= ewer; w += 2)
                    m = fmaxf(fmaxf(m, e1[w]), e1[w + 1]);
                if (w < ewer) m = fmaxf(m, e1[w]);
                vals1[ph - 1] = empty ? 0.0f : m;
            }
            phs = hs; phe = he;
        }
        {   // tail: reduce phase 6 (buffer 6&1=0 -> bufA)
            bool empty = (phe <= phs) || (ewe <= ews);
            float m = -FLT_MAX;
            int w = ewsr;
            for (; w + 2 <= ewer; w += 2)
                m = fmaxf(fmaxf(m, erA0[w]), erA0[w + 1]);
            if (w < ewer) m = fmaxf(m, erA0[w]);
            vals0[PH - 1] = empty ? 0.0f : m;
            m = -FLT_MAX;
            w = ewsr;
            for (; w + 2 <= ewer; w += 2)
                m = fmaxf(fmaxf(m, erA1[w]), erA1[w + 1]);
            if (w < ewer) m = fmaxf(m, erA1[w]);
            vals1[PH - 1] = empty ? 0.0f : m;
        }
        // stage 784 outputs then write coalesced (U[wv] reuse is wave-sync safe)
        float* stage = U[wv];
        if (eact) {
            #pragma unroll
            for (int ph = 0; ph < PH; ++ph) {
                stage[ech * 49 + ph * 7 + epw] = vals0[ph];
                stage[(8 + ech) * 49 + ph * 7 + epw] = vals1[ph];
            }
        }
        size_t obase = ((size_t)(r << 9) + c0) * 49;
        #pragma unroll
        for (int it = 0; it < 13; ++it) {
            int f = (it << 6) + lane;
            if (f < 784) out[obase + f] = stage[f];
        }
        return;
    }

    // ---- standard (5-8 quads) / dual (9-16 quads) paths: unchanged R17 ----
    int c0    = (cg << 5) + (wv << 3);
    int chsub = lane >> 3;           // 0..7
    int cq8   = lane & 7;
    bool dual = nq > 8;
    int cbase = ((b << 9) + c0 + chsub) << 10;
    int qabs0 = qs + cq8;
    int qabs1 = qs + 8 + cq8;
    bool m0 = qabs0 < qe;
    bool m1 = qabs1 < qe;
    int qc1 = min(qabs1, 15);        // clamped (dual tile1 only)
    float* bufB = U[wv] + 544;       // [8][68] each

    const float* erowA = bufA + (ech & 7) * 68;
    const float* erowB = bufB + (ech & 7) * 68;
    float vals[PH];
    int phs = 0, phe = 0;

    float4 last0 = NEG4, last1 = NEG4;
    int last_h = -100;

    if (!dual) {
        #pragma unroll
        for (int ph = 0; ph < PH; ++ph) {
            int hs = B[1 + ph], he = B[8 + ph];
            float* cw = (ph & 1) ? bufB : bufA;
            if (m0 && he > hs) {
                bool reuse = (hs == last_h);
                float4 a0 = reuse ? last0 : NEG4;
                int h0 = hs + (reuse ? 1 : 0);
                int nbody = he - h0 - 1;
                int idx = cbase + (h0 << 4) + qabs0;
                while (nbody >= 4) {
                    float4 v0 = f4[idx];
                    float4 v1 = f4[idx + 16];
                    float4 v2 = f4[idx + 32];
                    float4 v3 = f4[idx + 48];
                    a0 = max4(a0, max4(max4(v0, v1), max4(v2, v3)));
                    idx += 64; nbody -= 4;
                }
                if (nbody >= 2) {
                    float4 v0 = f4[idx];
                    float4 v1 = f4[idx + 16];
                    a0 = max4(a0, max4(v0, v1));
                    idx += 32; nbody -= 2;
                }
                if (nbody >= 1) a0 = max4(a0, f4[idx]);
                if (he - 1 >= h0) {
                    last0 = f4[cbase + ((he - 1) << 4) + qabs0];
                    a0 = max4(a0, last0);
                }
                last_h = he - 1;
                *(float4*)&cw[chsub * 68 + (qabs0 << 2)] = a0;
            }
            if (ph > 0) {
                const float* er = (ph & 1) ? erowA : erowB;
                float m = -FLT_MAX;
                int w = ews;
                for (; w + 2 <= ewe; w += 2)
                    m = fmaxf(fmaxf(m, er[w]), er[w + 1]);
                if (w < ewe) m = fmaxf(m, er[w]);
                vals[ph - 1] = ((phe <= phs) || (ewe <= ews)) ? 0.0f : m;
            }
            phs = hs; phe = he;
        }
    } else {
        #pragma unroll
        for (int ph = 0; ph < PH; ++ph) {
            int hs = B[1 + ph], he = B[8 + ph];
            float* cw = (ph & 1) ? bufB : bufA;
            if (he > hs) {
                bool reuse = (hs == last_h);
                float4 a0 = reuse ? last0 : NEG4;
                float4 a1 = reuse ? last1 : NEG4;
                int h0 = hs + (reuse ? 1 : 0);
                int nbody = he - h0 - 1;
                int idx = cbase + (h0 << 4);
                while (nbody >= 2) {
                    float4 v00 = f4[idx + qabs0];
                    float4 v01 = f4[idx + qc1];
                    float4 v10 = f4[idx + 16 + qabs0];
                    float4 v11 = f4[idx + 16 + qc1];
                    a0 = max4(a0, max4(v00, v10));
                    a1 = max4(a1, max4(v01, v11));
                    idx += 32; nbody -= 2;
                }
                if (nbody >= 1) {
                    a0 = max4(a0, f4[idx + qabs0]);
                    a1 = max4(a1, f4[idx + qc1]);
                }
                if (he - 1 >= h0) {
                    int fin = cbase + ((he - 1) << 4);
                    last0 = f4[fin + qabs0];
                    last1 = f4[fin + qc1];
                    a0 = max4(a0, last0);
                    a1 = max4(a1, last1);
                }
                last_h = he - 1;
                *(float4*)&cw[chsub * 68 + (qabs0 << 2)] = a0;
                if (m1) *(float4*)&cw[chsub * 68 + (qabs1 << 2)] = a1;
            }
            if (ph > 0) {
                const float* er = (ph & 1) ? erowA : erowB;
                float m = -FLT_MAX;
                int w = ews;
                for (; w + 2 <= ewe; w += 2)
                    m = fmaxf(fmaxf(m, er[w]), er[w + 1]);
                if (w < ewe) m = fmaxf(m, er[w]);
                vals[ph - 1] = ((phe <= phs) || (ewe <= ews)) ? 0.0f : m;
            }
            phs = hs; phe = he;
        }
    }
    {   // tail: reduce phase 6 (buffer 6&1=0 -> bufA)
        float m = -FLT_MAX;
        int w = ews;
        for (; w + 2 <= ewe; w += 2)
            m = fmaxf(fmaxf(m, erowA[w]), erowA[w + 1]);
        if (w < ewe) m = fmaxf(m, erowA[w]);
        vals[PH - 1] = ((phe <= phs) || (ewe <= ews)) ? 0.0f : m;
    }

    // stage the wave's 392 outputs then write coalesced (wave-sync safe reuse)
    float* stage = U[wv];
    if (eact) {
        #pragma unroll
        for (int ph = 0; ph < PH; ++ph)
            stage[ech * 49 + ph * 7 + epw] = vals[ph];
    }
    size_t obase = ((size_t)(r << 9) + c0) * 49;
    #pragma unroll
    for (int it = 0; it < 7; ++it) {
        int f = (it << 6) + lane;
        if (f < 392) out[obase + f] = stage[f];
    }
}

extern "C" void kernel_launch(void* const* d_in, const int* in_sizes, int n_in,
                              void* d_out, int out_size, void* d_ws, size_t ws_size,
                              hipStream_t stream) {
    const float* features = (const float*)d_in[0];
    const float* rois     = (const float*)d_in[1];
    float* out = (float*)d_out;
    int* wsbuf = (int*)d_ws;

    int R = in_sizes[1] / 5;   // 2000

    roi_bounds_kernel<<<(R + 255) / 256, 256, 0, stream>>>(rois, wsbuf, R);
    roipool_main<<<R * 16, 256, 0, stream>>>(features, wsbuf, out);
}

// Round 21
// 179.532 us; speedup vs baseline: 1.5680x; 1.1742x over previous
//
#include <hip/hip_runtime.h>
#include <math.h>
#include <float.h>

#define PH 7
#define RLEN 32   // ints per roi in workspace

// ---- exact integer emulation of the reference's fast-math f32 binning ----
// bin = RN_f32(roi * RN_f32(1/7));  RN_f32(1/7) = 9586981 * 2^-26
#define C7 9586981LL

__device__ __forceinline__ long long round24(long long v) {
    if (v == 0) return 0;
    int L = 64 - __clzll((unsigned long long)v);
    int sh = L - 24;
    if (sh <= 0) return v;
    long long rem  = v & ((1LL << sh) - 1);
    long long base = v >> sh;
    long long half = 1LL << (sh - 1);
    if (rem > half || (rem == half && (base & 1))) base++;
    return base << sh;
}
__device__ __forceinline__ long long bin_q26(int roi) {
    return round24((long long)roi * C7);
}
__device__ __forceinline__ int floor_k(long long b26, int k) {
    long long v = round24((long long)k * b26);
    return (int)(v >> 26);
}
__device__ __forceinline__ int ceil_k(long long b26, int k) {
    long long v = round24((long long)k * b26);
    return (int)((v + ((1LL << 26) - 1)) >> 26);
}

// Per-ROI bounds (ints): [0]=b, [1..7]=hstart, [8..14]=hend,
// [15] = qs | qe<<8 (window column-quad range), [16..22]=ws, [23..29]=we
__global__ void roi_bounds_kernel(const float* __restrict__ rois,
                                  int* __restrict__ wsbuf, int R) {
    int r = blockIdx.x * blockDim.x + threadIdx.x;
    if (r >= R) return;
    const int H = 64, W = 64;
    const float* roi = rois + r * 5;
    int b  = (int)roi[0];
    int x1 = (int)rintf(roi[1] * 0.0625f);
    int y1 = (int)rintf(roi[2] * 0.0625f);
    int x2 = (int)rintf(roi[3] * 0.0625f);
    int y2 = (int)rintf(roi[4] * 0.0625f);

    int roi_w = max(x2 - x1 + 1, 1);
    int roi_h = max(y2 - y1 + 1, 1);
    long long bh = bin_q26(roi_h);
    long long bw = bin_q26(roi_w);

    int* o = wsbuf + r * RLEN;
    o[0] = b;
    int ws0 = 64, we6 = 0;
    #pragma unroll
    for (int i = 0; i < PH; ++i) {
        int hs = min(max(y1 + floor_k(bh, i),     0), H);
        int he = min(max(y1 + ceil_k (bh, i + 1), 0), H);
        int wst = min(max(x1 + floor_k(bw, i),     0), W);
        int wen = min(max(x1 + ceil_k (bw, i + 1), 0), W);
        o[1 + i]  = hs;
        o[8 + i]  = he;
        o[16 + i] = wst;
        o[23 + i] = wen;
        if (i == 0) ws0 = wst;
        if (i == 6) we6 = wen;
    }
    int qs = ws0 >> 2;
    int qe = (we6 + 3) >> 2;
    o[15] = qs | (max(qe, qs) << 8);
}

// Deterministic counting sort of ROI indices by image b (4 buckets).
// One wave; ballot+popcount scatter preserves original order within buckets.
__global__ void roi_sort_kernel(const float* __restrict__ rois,
                                int* __restrict__ order, int R) {
    int lane = threadIdx.x;          // blockDim = 64
    // pass 1: totals per bucket (order-independent)
    int cnt0 = 0, cnt1 = 0, cnt2 = 0, cnt3 = 0;
    for (int i = lane; i < R; i += 64) {
        int b = (int)rois[i * 5];
        cnt0 += (b == 0); cnt1 += (b == 1); cnt2 += (b == 2); cnt3 += (b == 3);
    }
    #pragma unroll
    for (int s = 32; s > 0; s >>= 1) {
        cnt0 += __shfl_down(cnt0, s);
        cnt1 += __shfl_down(cnt1, s);
        cnt2 += __shfl_down(cnt2, s);
        cnt3 += __shfl_down(cnt3, s);
    }
    int off0 = 0, off1, off2, off3;
    off1 = __shfl(cnt0, 0);
    off2 = off1 + __shfl(cnt1, 0);
    off3 = off2 + __shfl(cnt2, 0);
    // pass 2: stable scatter, 64 at a time
    unsigned long long below = (1ull << lane) - 1ull;
    for (int base = 0; base < R; base += 64) {
        int i = base + lane;
        int b = (i < R) ? (int)rois[i * 5] : -1;
        unsigned long long m0 = __ballot(b == 0);
        unsigned long long m1 = __ballot(b == 1);
        unsigned long long m2 = __ballot(b == 2);
        unsigned long long m3 = __ballot(b == 3);
        if (b == 0) order[off0 + __popcll(m0 & below)] = i;
        if (b == 1) order[off1 + __popcll(m1 & below)] = i;
        if (b == 2) order[off2 + __popcll(m2 & below)] = i;
        if (b == 3) order[off3 + __popcll(m3 & below)] = i;
        off0 += __popcll(m0); off1 += __popcll(m1);
        off2 += __popcll(m2); off3 += __popcll(m3);
    }
}

__device__ __forceinline__ float4 max4(float4 a, float4 b) {
    float4 r;
    r.x = fmaxf(a.x, b.x); r.y = fmaxf(a.y, b.y);
    r.z = fmaxf(a.z, b.z); r.w = fmaxf(a.w, b.w);
    return r;
}

// R17 structure (row carry, dual-tile single pass, double-buffered cm with
// one-phase-lagged reduce, no barriers) + b-SORTED PROCESSING ORDER:
// blocks process ROIs grouped by image, shrinking each XCD's L2 working set
// from 16 MB (4 images) to 1 MB (1 image). Output still goes to slot r.
// Block = 256 threads = 4 independent waves. Grid = R * 16.
__global__ __launch_bounds__(256) void roipool_main(
        const float* __restrict__ features,
        const int* __restrict__ wsbuf,
        const int* __restrict__ order,
        float* __restrict__ out) {
    __shared__ float cmA[4][8][68];   // 8704 B
    __shared__ float cmB[4][8][68];   // 8704 B

    int r    = order[blockIdx.x >> 4];   // b-sorted processing order
    int cg   = blockIdx.x & 15;
    int wv   = threadIdx.x >> 6;
    int lane = threadIdx.x & 63;
    int chsub = lane >> 3;           // 0..7: channel within wave
    int cq8   = lane & 7;            // quad slot within tile
    int c0   = (cg << 5) + (wv << 3);

    const int* B = wsbuf + r * RLEN; // wave-uniform -> scalar loads
    int b   = B[0];
    int qpk = B[15];
    int qs  = qpk & 255;
    int qe  = qpk >> 8;
    bool dual = (qe - qs) > 8;

    const float4* f4 = (const float4*)features;
    int cbase = ((b << 9) + c0 + chsub) << 10;
    int qabs0 = qs + cq8;
    int qabs1 = qs + 8 + cq8;
    bool m0 = qabs0 < qe;
    bool m1 = qabs1 < qe;
    int qc1 = min(qabs1, 15);        // clamped (dual tile1 only)

    // epilogue lane mapping (8 ch * 7 pw = 56 active lanes)
    int ech = (lane * 9363) >> 16;   // lane/7 for lane<56
    int epw = lane - ech * 7;
    int ews = B[16 + epw];           // per-lane, L1-hot
    int ewe = B[23 + epw];
    bool eact = lane < 56;
    const float* erowA = cmA[wv][ech & 7];
    const float* erowB = cmB[wv][ech & 7];
    float vals[PH];
    int phs = 0, phe = 0;            // previous phase h-bounds (for lag)

    const float4 NEG4 = make_float4(-FLT_MAX, -FLT_MAX, -FLT_MAX, -FLT_MAX);
    float4 last0 = NEG4, last1 = NEG4;   // final-row carry
    int last_h = -100;

    if (!dual) {
        #pragma unroll
        for (int ph = 0; ph < PH; ++ph) {
            int hs = B[1 + ph], he = B[8 + ph];   // wave-uniform scalars
            float (*cw)[68] = (ph & 1) ? cmB[wv] : cmA[wv];
            if (m0 && he > hs) {                  // masked: idle lanes skip loads
                bool reuse = (hs == last_h);
                float4 a0 = reuse ? last0 : NEG4;
                int h0 = hs + (reuse ? 1 : 0);
                int nbody = he - h0 - 1;          // rows before the final row
                int idx = cbase + (h0 << 4) + qabs0;
                while (nbody >= 4) {              // 4 loads in flight
                    float4 v0 = f4[idx];
                    float4 v1 = f4[idx + 16];
                    float4 v2 = f4[idx + 32];
                    float4 v3 = f4[idx + 48];
                    a0 = max4(a0, max4(max4(v0, v1), max4(v2, v3)));
                    idx += 64; nbody -= 4;
                }
                if (nbody >= 2) {
                    float4 v0 = f4[idx];
                    float4 v1 = f4[idx + 16];
                    a0 = max4(a0, max4(v0, v1));
                    idx += 32; nbody -= 2;
                }
                if (nbody >= 1) a0 = max4(a0, f4[idx]);
                if (he - 1 >= h0) {               // final row: load once, carry
                    last0 = f4[cbase + ((he - 1) << 4) + qabs0];
                    a0 = max4(a0, last0);
                }
                last_h = he - 1;
                *(float4*)&cw[chsub][qabs0 << 2] = a0;
            }
            if (ph > 0) {                         // lagged reduce of ph-1
                const float* er = (ph & 1) ? erowA : erowB;
                float m = -FLT_MAX;
                int w = ews;
                for (; w + 2 <= ewe; w += 2)
                    m = fmaxf(fmaxf(m, er[w]), er[w + 1]);
                if (w < ewe) m = fmaxf(m, er[w]);
                vals[ph - 1] = ((phe <= phs) || (ewe <= ews)) ? 0.0f : m;
            }
            phs = hs; phe = he;
        }
    } else {
        #pragma unroll
        for (int ph = 0; ph < PH; ++ph) {
            int hs = B[1 + ph], he = B[8 + ph];
            float (*cw)[68] = (ph & 1) ? cmB[wv] : cmA[wv];
            if (he > hs) {                        // tile0 fully active in dual
                bool reuse = (hs == last_h);
                float4 a0 = reuse ? last0 : NEG4;
                float4 a1 = reuse ? last1 : NEG4;
                int h0 = hs + (reuse ? 1 : 0);
                int nbody = he - h0 - 1;
                int idx = cbase + (h0 << 4);
                while (nbody >= 2) {              // 4 loads in flight (2 rows x 2 tiles)
                    float4 v00 = f4[idx + qabs0];
                    float4 v01 = f4[idx + qc1];
                    float4 v10 = f4[idx + 16 + qabs0];
                    float4 v11 = f4[idx + 16 + qc1];
                    a0 = max4(a0, max4(v00, v10));
                    a1 = max4(a1, max4(v01, v11));
                    idx += 32; nbody -= 2;
                }
                if (nbody >= 1) {
                    a0 = max4(a0, f4[idx + qabs0]);
                    a1 = max4(a1, f4[idx + qc1]);
                }
                if (he - 1 >= h0) {
                    int fin = cbase + ((he - 1) << 4);
                    last0 = f4[fin + qabs0];
                    last1 = f4[fin + qc1];
                    a0 = max4(a0, last0);
                    a1 = max4(a1, last1);
                }
                last_h = he - 1;
                *(float4*)&cw[chsub][qabs0 << 2] = a0;
                if (m1) *(float4*)&cw[chsub][qabs1 << 2] = a1;
            }
            if (ph > 0) {                         // lagged reduce of ph-1
                const float* er = (ph & 1) ? erowA : erowB;
                float m = -FLT_MAX;
                int w = ews;
                for (; w + 2 <= ewe; w += 2)
                    m = fmaxf(fmaxf(m, er[w]), er[w + 1]);
                if (w < ewe) m = fmaxf(m, er[w]);
                vals[ph - 1] = ((phe <= phs) || (ewe <= ews)) ? 0.0f : m;
            }
            phs = hs; phe = he;
        }
    }
    {   // tail: reduce phase 6 (buffer 6&1 = 0 -> cmA)
        float m = -FLT_MAX;
        int w = ews;
        for (; w + 2 <= ewe; w += 2)
            m = fmaxf(fmaxf(m, erowA[w]), erowA[w + 1]);
        if (w < ewe) m = fmaxf(m, erowA[w]);
        vals[PH - 1] = ((phe <= phs) || (ewe <= ews)) ? 0.0f : m;
    }

    // stage the wave's 392 outputs (k = ech*49 + ph*7 + epw) then write
    // coalesced; cmA reuse is safe after the final reduce (wave-sync).
    float* stage = (float*)cmA[wv];
    if (eact) {
        #pragma unroll
        for (int ph = 0; ph < PH; ++ph)
            stage[ech * 49 + ph * 7 + epw] = vals[ph];
    }
    size_t obase = ((size_t)(r << 9) + c0) * 49;
    #pragma unroll
    for (int it = 0; it < 7; ++it) {
        int f = (it << 6) + lane;
        if (f < 392) out[obase + f] = stage[f];
    }
}

extern "C" void kernel_launch(void* const* d_in, const int* in_sizes, int n_in,
                              void* d_out, int out_size, void* d_ws, size_t ws_size,
                              hipStream_t stream) {
    const float* features = (const float*)d_in[0];
    const float* rois     = (const float*)d_in[1];
    float* out = (float*)d_out;
    int* wsbuf = (int*)d_ws;

    int R = in_sizes[1] / 5;   // 2000
    int* order = wsbuf + R * RLEN;   // 2000 ints after the bounds table

    roi_bounds_kernel<<<(R + 255) / 256, 256, 0, stream>>>(rois, wsbuf, R);
    roi_sort_kernel<<<1, 64, 0, stream>>>(rois, order, R);
    roipool_main<<<R * 16, 256, 0, stream>>>(features, wsbuf, order, out);
}

// Round 23
// 176.569 us; speedup vs baseline: 1.5943x; 1.0168x over previous
//
#include <hip/hip_runtime.h>
#include <math.h>
#include <float.h>

#define PH 7
#define RLEN 32   // ints per roi in workspace

// ---- exact integer emulation of the reference's fast-math f32 binning ----
// bin = RN_f32(roi * RN_f32(1/7));  RN_f32(1/7) = 9586981 * 2^-26
#define C7 9586981LL

typedef float nt4 __attribute__((ext_vector_type(4)));   // NT-store-compatible

__device__ __forceinline__ long long round24(long long v) {
    if (v == 0) return 0;
    int L = 64 - __clzll((unsigned long long)v);
    int sh = L - 24;
    if (sh <= 0) return v;
    long long rem  = v & ((1LL << sh) - 1);
    long long base = v >> sh;
    long long half = 1LL << (sh - 1);
    if (rem > half || (rem == half && (base & 1))) base++;
    return base << sh;
}
__device__ __forceinline__ long long bin_q26(int roi) {
    return round24((long long)roi * C7);
}
__device__ __forceinline__ int floor_k(long long b26, int k) {
    long long v = round24((long long)k * b26);
    return (int)(v >> 26);
}
__device__ __forceinline__ int ceil_k(long long b26, int k) {
    long long v = round24((long long)k * b26);
    return (int)((v + ((1LL << 26) - 1)) >> 26);
}

// Per-ROI bounds (ints): [0]=b, [1..7]=hstart, [8..14]=hend,
// [15] = qs | qe<<8 (window column-quad range), [16..22]=ws, [23..29]=we
__global__ void roi_bounds_kernel(const float* __restrict__ rois,
                                  int* __restrict__ wsbuf, int R) {
    int r = blockIdx.x * blockDim.x + threadIdx.x;
    if (r >= R) return;
    const int H = 64, W = 64;
    const float* roi = rois + r * 5;
    int b  = (int)roi[0];
    int x1 = (int)rintf(roi[1] * 0.0625f);
    int y1 = (int)rintf(roi[2] * 0.0625f);
    int x2 = (int)rintf(roi[3] * 0.0625f);
    int y2 = (int)rintf(roi[4] * 0.0625f);

    int roi_w = max(x2 - x1 + 1, 1);
    int roi_h = max(y2 - y1 + 1, 1);
    long long bh = bin_q26(roi_h);
    long long bw = bin_q26(roi_w);

    int* o = wsbuf + r * RLEN;
    o[0] = b;
    int ws0 = 64, we6 = 0;
    #pragma unroll
    for (int i = 0; i < PH; ++i) {
        int hs = min(max(y1 + floor_k(bh, i),     0), H);
        int he = min(max(y1 + ceil_k (bh, i + 1), 0), H);
        int wst = min(max(x1 + floor_k(bw, i),     0), W);
        int wen = min(max(x1 + ceil_k (bw, i + 1), 0), W);
        o[1 + i]  = hs;
        o[8 + i]  = he;
        o[16 + i] = wst;
        o[23 + i] = wen;
        if (i == 0) ws0 = wst;
        if (i == 6) we6 = wen;
    }
    int qs = ws0 >> 2;
    int qe = (we6 + 3) >> 2;
    o[15] = qs | (max(qe, qs) << 8);
}

// Deterministic counting sort of ROI indices by image b (4 buckets).
// One wave; ballot+popcount scatter preserves original order within buckets.
__global__ void roi_sort_kernel(const float* __restrict__ rois,
                                int* __restrict__ order, int R) {
    int lane = threadIdx.x;          // blockDim = 64
    int cnt0 = 0, cnt1 = 0, cnt2 = 0, cnt3 = 0;
    for (int i = lane; i < R; i += 64) {
        int b = (int)rois[i * 5];
        cnt0 += (b == 0); cnt1 += (b == 1); cnt2 += (b == 2); cnt3 += (b == 3);
    }
    #pragma unroll
    for (int s = 32; s > 0; s >>= 1) {
        cnt0 += __shfl_down(cnt0, s);
        cnt1 += __shfl_down(cnt1, s);
        cnt2 += __shfl_down(cnt2, s);
        cnt3 += __shfl_down(cnt3, s);
    }
    int off0 = 0, off1, off2, off3;
    off1 = __shfl(cnt0, 0);
    off2 = off1 + __shfl(cnt1, 0);
    off3 = off2 + __shfl(cnt2, 0);
    unsigned long long below = (1ull << lane) - 1ull;
    for (int base = 0; base < R; base += 64) {
        int i = base + lane;
        int b = (i < R) ? (int)rois[i * 5] : -1;
        unsigned long long m0 = __ballot(b == 0);
        unsigned long long m1 = __ballot(b == 1);
        unsigned long long m2 = __ballot(b == 2);
        unsigned long long m3 = __ballot(b == 3);
        if (b == 0) order[off0 + __popcll(m0 & below)] = i;
        if (b == 1) order[off1 + __popcll(m1 & below)] = i;
        if (b == 2) order[off2 + __popcll(m2 & below)] = i;
        if (b == 3) order[off3 + __popcll(m3 & below)] = i;
        off0 += __popcll(m0); off1 += __popcll(m1);
        off2 += __popcll(m2); off3 += __popcll(m3);
    }
}

__device__ __forceinline__ float4 max4(float4 a, float4 b) {
    float4 r;
    r.x = fmaxf(a.x, b.x); r.y = fmaxf(a.y, b.y);
    r.z = fmaxf(a.z, b.z); r.w = fmaxf(a.w, b.w);
    return r;
}

// R21 structure (row carry, dual-tile single pass, double-buffered cm with
// one-phase-lagged reduce, b-sorted processing order, no barriers)
// + float4 nontemporal final write (via ext_vector_type alias).
// Block = 256 threads = 4 independent waves. Grid = R * 16.
__global__ __launch_bounds__(256) void roipool_main(
        const float* __restrict__ features,
        const int* __restrict__ wsbuf,
        const int* __restrict__ order,
        float* __restrict__ out) {
    __shared__ float cmA[4][8][68];   // 8704 B
    __shared__ float cmB[4][8][68];   // 8704 B

    int r    = order[blockIdx.x >> 4];   // b-sorted processing order
    int cg   = blockIdx.x & 15;
    int wv   = threadIdx.x >> 6;
    int lane = threadIdx.x & 63;
    int chsub = lane >> 3;           // 0..7: channel within wave
    int cq8   = lane & 7;            // quad slot within tile
    int c0   = (cg << 5) + (wv << 3);

    const int* B = wsbuf + r * RLEN; // wave-uniform -> scalar loads
    int b   = B[0];
    int qpk = B[15];
    int qs  = qpk & 255;
    int qe  = qpk >> 8;
    bool dual = (qe - qs) > 8;

    const float4* f4 = (const float4*)features;
    int cbase = ((b << 9) + c0 + chsub) << 10;
    int qabs0 = qs + cq8;
    int qabs1 = qs + 8 + cq8;
    bool m0 = qabs0 < qe;
    bool m1 = qabs1 < qe;
    int qc1 = min(qabs1, 15);        // clamped (dual tile1 only)

    // epilogue lane mapping (8 ch * 7 pw = 56 active lanes)
    int ech = (lane * 9363) >> 16;   // lane/7 for lane<56
    int epw = lane - ech * 7;
    int ews = B[16 + epw];           // per-lane, L1-hot
    int ewe = B[23 + epw];
    bool eact = lane < 56;
    const float* erowA = cmA[wv][ech & 7];
    const float* erowB = cmB[wv][ech & 7];
    float vals[PH];
    int phs = 0, phe = 0;            // previous phase h-bounds (for lag)

    const float4 NEG4 = make_float4(-FLT_MAX, -FLT_MAX, -FLT_MAX, -FLT_MAX);
    float4 last0 = NEG4, last1 = NEG4;   // final-row carry
    int last_h = -100;

    if (!dual) {
        #pragma unroll
        for (int ph = 0; ph < PH; ++ph) {
            int hs = B[1 + ph], he = B[8 + ph];   // wave-uniform scalars
            float (*cw)[68] = (ph & 1) ? cmB[wv] : cmA[wv];
            if (m0 && he > hs) {                  // masked: idle lanes skip loads
                bool reuse = (hs == last_h);
                float4 a0 = reuse ? last0 : NEG4;
                int h0 = hs + (reuse ? 1 : 0);
                int nbody = he - h0 - 1;          // rows before the final row
                int idx = cbase + (h0 << 4) + qabs0;
                while (nbody >= 4) {              // 4 loads in flight
                    float4 v0 = f4[idx];
                    float4 v1 = f4[idx + 16];
                    float4 v2 = f4[idx + 32];
                    float4 v3 = f4[idx + 48];
                    a0 = max4(a0, max4(max4(v0, v1), max4(v2, v3)));
                    idx += 64; nbody -= 4;
                }
                if (nbody >= 2) {
                    float4 v0 = f4[idx];
                    float4 v1 = f4[idx + 16];
                    a0 = max4(a0, max4(v0, v1));
                    idx += 32; nbody -= 2;
                }
                if (nbody >= 1) a0 = max4(a0, f4[idx]);
                if (he - 1 >= h0) {               // final row: load once, carry
                    last0 = f4[cbase + ((he - 1) << 4) + qabs0];
                    a0 = max4(a0, last0);
                }
                last_h = he - 1;
                *(float4*)&cw[chsub][qabs0 << 2] = a0;
            }
            if (ph > 0) {                         // lagged reduce of ph-1
                const float* er = (ph & 1) ? erowA : erowB;
                float m = -FLT_MAX;
                int w = ews;
                for (; w + 2 <= ewe; w += 2)
                    m = fmaxf(fmaxf(m, er[w]), er[w + 1]);
                if (w < ewe) m = fmaxf(m, er[w]);
                vals[ph - 1] = ((phe <= phs) || (ewe <= ews)) ? 0.0f : m;
            }
            phs = hs; phe = he;
        }
    } else {
        #pragma unroll
        for (int ph = 0; ph < PH; ++ph) {
            int hs = B[1 + ph], he = B[8 + ph];
            float (*cw)[68] = (ph & 1) ? cmB[wv] : cmA[wv];
            if (he > hs) {                        // tile0 fully active in dual
                bool reuse = (hs == last_h);
                float4 a0 = reuse ? last0 : NEG4;
                float4 a1 = reuse ? last1 : NEG4;
                int h0 = hs + (reuse ? 1 : 0);
                int nbody = he - h0 - 1;
                int idx = cbase + (h0 << 4);
                while (nbody >= 2) {              // 4 loads in flight (2 rows x 2 tiles)
                    float4 v00 = f4[idx + qabs0];
                    float4 v01 = f4[idx + qc1];
                    float4 v10 = f4[idx + 16 + qabs0];
                    float4 v11 = f4[idx + 16 + qc1];
                    a0 = max4(a0, max4(v00, v10));
                    a1 = max4(a1, max4(v01, v11));
                    idx += 32; nbody -= 2;
                }
                if (nbody >= 1) {
                    a0 = max4(a0, f4[idx + qabs0]);
                    a1 = max4(a1, f4[idx + qc1]);
                }
                if (he - 1 >= h0) {
                    int fin = cbase + ((he - 1) << 4);
                    last0 = f4[fin + qabs0];
                    last1 = f4[fin + qc1];
                    a0 = max4(a0, last0);
                    a1 = max4(a1, last1);
                }
                last_h = he - 1;
                *(float4*)&cw[chsub][qabs0 << 2] = a0;
                if (m1) *(float4*)&cw[chsub][qabs1 << 2] = a1;
            }
            if (ph > 0) {                         // lagged reduce of ph-1
                const float* er = (ph & 1) ? erowA : erowB;
                float m = -FLT_MAX;
                int w = ews;
                for (; w + 2 <= ewe; w += 2)
                    m = fmaxf(fmaxf(m, er[w]), er[w + 1]);
                if (w < ewe) m = fmaxf(m, er[w]);
                vals[ph - 1] = ((phe <= phs) || (ewe <= ews)) ? 0.0f : m;
            }
            phs = hs; phe = he;
        }
    }
    {   // tail: reduce phase 6 (buffer 6&1 = 0 -> cmA)
        float m = -FLT_MAX;
        int w = ews;
        for (; w + 2 <= ewe; w += 2)
            m = fmaxf(fmaxf(m, erowA[w]), erowA[w + 1]);
        if (w < ewe) m = fmaxf(m, erowA[w]);
        vals[PH - 1] = ((phe <= phs) || (ewe <= ews)) ? 0.0f : m;
    }

    // stage the wave's 392 outputs (k = ech*49 + ph*7 + epw), then write as
    // 98 nontemporal float4 (fully-written lines; keeps L2 for features).
    float* stage = (float*)cmA[wv];
    if (eact) {
        #pragma unroll
        for (int ph = 0; ph < PH; ++ph)
            stage[ech * 49 + ph * 7 + epw] = vals[ph];
    }
    const nt4* stage4 = (const nt4*)stage;         // 16B-aligned (LDS array)
    size_t obase = ((size_t)(r << 9) + c0) * 49;   // multiple of 8*49 -> 16B aligned
    nt4* out4 = (nt4*)&out[obase];
    #pragma unroll
    for (int it = 0; it < 2; ++it) {
        int f = (it << 6) + lane;
        if (f < 98) __builtin_nontemporal_store(stage4[f], &out4[f]);
    }
}

extern "C" void kernel_launch(void* const* d_in, const int* in_sizes, int n_in,
                              void* d_out, int out_size, void* d_ws, size_t ws_size,
                              hipStream_t stream) {
    const float* features = (const float*)d_in[0];
    const float* rois     = (const float*)d_in[1];
    float* out = (float*)d_out;
    int* wsbuf = (int*)d_ws;

    int R = in_sizes[1] / 5;   // 2000
    int* order = wsbuf + R * RLEN;   // 2000 ints after the bounds table

    roi_bounds_kernel<<<(R + 255) / 256, 256, 0, stream>>>(rois, wsbuf, R);
    roi_sort_kernel<<<1, 64, 0, stream>>>(rois, order, R);
    roipool_main<<<R * 16, 256, 0, stream>>>(features, wsbuf, order, out);
}